// Round 6
// baseline (279.369 us; speedup 1.0000x reference)
//
#include <hip/hip_runtime.h>
#include <math.h>

#define NXC 432
#define NYC 496
#define CELLS (NYC * NXC)          // 214272
#define BATCH 4
#define PTOT 48000
#define EPSC 1e-3f
#define TCELLS 128                 // emit tile (CELLS % 128 == 0)

typedef float f4v __attribute__((ext_vector_type(4)));

__device__ __forceinline__ float bcast_first(float x) {
    return __int_as_float(__builtin_amdgcn_readfirstlane(__float_as_int(x)));
}

// ---------------------------------------------------------------------------
// Kernel 1: per-pillar fused PFN1 + PFN2 + BN + ReLU + max + attention mix.
// One wave per pillar; lane = output channel f.
// DIAGNOSTIC ROUND: launched 5x (idempotent) to measure t_pfe from dur delta.
// ---------------------------------------------------------------------------
__global__ __launch_bounds__(256) void pfe_kernel(
    const float* __restrict__ pillars, const float* __restrict__ w1,
    const float* __restrict__ bn1, const float* __restrict__ w2,
    const float* __restrict__ bn2, const float* __restrict__ wf1,
    const float* __restrict__ wf2, const float* __restrict__ fbn1,
    const float* __restrict__ fbn2, const int* __restrict__ coords,
    const int* __restrict__ num_points, float* __restrict__ comb,
    int* __restrict__ map)
{
    const int tid  = threadIdx.x;
    const int lane = tid & 63;
    // wave-uniform pillar index (provably uniform for the compiler)
    const int p = __builtin_amdgcn_readfirstlane(blockIdx.x * 4 + (tid >> 6));
    const float* __restrict__ pl = pillars + (size_t)p * 256;

    // --- mean xyz over all 32 points (reference does NOT mask), / num_points
    float sx = 0.f, sy = 0.f, sz = 0.f;
    if (lane < 32) {
        const f4v v = *(const f4v*)(pl + lane * 8);
        sx = v.x; sy = v.y; sz = v.z;
    }
#pragma unroll
    for (int off = 16; off; off >>= 1) {
        sx += __shfl_xor(sx, off);
        sy += __shfl_xor(sy, off);
        sz += __shfl_xor(sz, off);
    }
    sx = bcast_first(sx); sy = bcast_first(sy); sz = bcast_first(sz);

    const float inv_np = 1.0f / (float)num_points[p];
    const float mxm = sx * inv_np, mym = sy * inv_np, mzm = sz * inv_np;

    const int c1 = coords[p * 4 + 1], c2 = coords[p * 4 + 2], c3 = coords[p * 4 + 3];
    const float cx = c3 * 0.16f + 0.08f;
    const float cy = c2 * 0.16f + (-39.6f);
    const float cz = c1 * 4.0f  + (-1.0f);

    const int f = lane;

    // fold PFN1: h1 = x*AX + y*AY + z*AZ + i*AI + C0 (BN scale folded in)
    const float g1 = bn1[f], be1 = bn1[64 + f], bm1 = bn1[128 + f], bv1 = bn1[192 + f];
    const float s1 = g1 * rsqrtf(bv1 + EPSC);
    const float w10 = w1[f],        w11 = w1[64 + f],  w12 = w1[128 + f], w13 = w1[192 + f];
    const float w14 = w1[256 + f],  w15 = w1[320 + f], w16 = w1[384 + f];
    const float w17 = w1[448 + f],  w18 = w1[512 + f], w19 = w1[576 + f];
    const float AX = (w10 + w14 + w17) * s1;
    const float AY = (w11 + w15 + w18) * s1;
    const float AZ = (w12 + w16 + w19) * s1;
    const float AI = w13 * s1;
    const float C0 = be1 - bm1 * s1
                   - (mxm * w14 + mym * w15 + mzm * w16) * s1
                   - (cx * w17 + cy * w18 + cz * w19) * s1;

    // fold PFN2
    const float g2 = bn2[f], be2 = bn2[64 + f], bm2 = bn2[128 + f], bv2 = bn2[192 + f];
    const float s2 = g2 * rsqrtf(bv2 + EPSC);
    const float b0 = w2[f] * s2,        b1 = w2[64 + f] * s2;
    const float b2 = w2[128 + f] * s2,  b3 = w2[192 + f] * s2;
    const float b4 = w2[256 + f] * s2,  b5 = w2[320 + f] * s2;
    const float b6 = w2[384 + f] * s2,  b7 = w2[448 + f] * s2;
    const float C2 = be2 - bm2 * s2;

    float max1 = -1e30f, max2 = -1e30f;
#pragma unroll
    for (int j = 0; j < 16; ++j) {
        float c[16];
#pragma unroll
        for (int k = 0; k < 16; ++k) c[k] = pl[j * 16 + k];

        const float h1a = fmaf(c[0], AX, fmaf(c[1], AY, fmaf(c[2], AZ, fmaf(c[3], AI, C0))));
        const float h1b = fmaf(c[8], AX, fmaf(c[9], AY, fmaf(c[10], AZ, fmaf(c[11], AI, C0))));
        const float h2a = fmaf(c[0], b0, fmaf(c[1], b1, fmaf(c[2], b2, fmaf(c[3], b3,
                          fmaf(c[4], b4, fmaf(c[5], b5, fmaf(c[6], b6, fmaf(c[7], b7, C2))))))));
        const float h2b = fmaf(c[8], b0, fmaf(c[9], b1, fmaf(c[10], b2, fmaf(c[11], b3,
                          fmaf(c[12], b4, fmaf(c[13], b5, fmaf(c[14], b6, fmaf(c[15], b7, C2))))))));
        max1 = fmaxf(max1, fmaxf(h1a, h1b));
        max2 = fmaxf(max2, fmaxf(h2a, h2b));
    }
    const float f1v = fmaxf(max1, 0.f);
    const float f2v = fmaxf(max2, 0.f);

    // attention scalars: s = bn(dot(f, wf))
    float d1 = f1v * wf1[f];
    float d2 = f2v * wf2[f];
#pragma unroll
    for (int off = 32; off; off >>= 1) {
        d1 += __shfl_xor(d1, off);
        d2 += __shfl_xor(d2, off);
    }
    const float sc1 = (d1 - fbn1[2]) * (fbn1[0] * rsqrtf(fbn1[3] + EPSC)) + fbn1[1];
    const float sc2 = (d2 - fbn2[2]) * (fbn2[0] * rsqrtf(fbn2[3] + EPSC)) + fbn2[1];
    const float a0 = 1.0f / (1.0f + expf(sc2 - sc1));   // softmax weight of branch 1

    comb[p * 64 + f] = fmaf(f1v - f2v, a0, f2v);        // f1*a0 + f2*(1-a0)

    if (lane == 0) {
        const int lin = c1 + c2 * NXC + c3;
        map[coords[p * 4 + 0] * CELLS + lin] = p;
    }
}

// ---------------------------------------------------------------------------
// Kernel 2: dense emit via LDS transpose (unchanged from round 5).
// ---------------------------------------------------------------------------
__global__ __launch_bounds__(256) void emit_kernel(
    const int* __restrict__ map, const float* __restrict__ comb,
    float* __restrict__ out)
{
    __shared__ float lds[64 * 132];           // [ch][cell], pad 132 words
    const int t = threadIdx.x;
    const int gbase = blockIdx.x * TCELLS;    // global cell base (tile in one batch)

    // phase 1: gather comb rows -> LDS transposed
    {
        const int c = t >> 1;                 // cell within tile
        const int h = (t & 1) * 32;           // channel half
        const int m = map[gbase + c];
        const float sel = (m < 0) ? 0.f : 1.f;
        const float* src = comb + (size_t)((m < 0) ? 0 : m) * 64 + h;
        float* dst = lds + h * 132 + c;
#pragma unroll
        for (int j = 0; j < 8; j++) {
            const float4 v = *(const float4*)(src + j * 4);
            dst[(j * 4 + 0) * 132] = v.x * sel;
            dst[(j * 4 + 1) * 132] = v.y * sel;
            dst[(j * 4 + 2) * 132] = v.z * sel;
            dst[(j * 4 + 3) * 132] = v.w * sel;
        }
    }
    __syncthreads();

    // phase 2: coalesced float4 nontemporal stores
    const int b = gbase / CELLS;
    const int L = gbase - b * CELLS;
    float* obase = out + (size_t)(b * 64) * CELLS + L;
#pragma unroll
    for (int r = 0; r < 8; r++) {
        const int idx = r * 256 + t;
        const int f = idx >> 5;               // channel
        const int g = idx & 31;               // float4 group along cells
        const f4v v = *(const f4v*)(lds + f * 132 + g * 4);
        __builtin_nontemporal_store(v, (f4v*)(obase + (size_t)f * CELLS + g * 4));
    }
}

extern "C" void kernel_launch(void* const* d_in, const int* in_sizes, int n_in,
                              void* d_out, int out_size, void* d_ws, size_t ws_size,
                              hipStream_t stream) {
    const float* pillars = (const float*)d_in[0];
    const float* w1      = (const float*)d_in[1];
    const float* bn1     = (const float*)d_in[2];
    const float* w2      = (const float*)d_in[3];
    const float* bn2     = (const float*)d_in[4];
    const float* wf1     = (const float*)d_in[5];
    const float* wf2     = (const float*)d_in[6];
    const float* fbn1    = (const float*)d_in[7];
    const float* fbn2    = (const float*)d_in[8];
    const int*   coords  = (const int*)d_in[9];
    const int*   nump    = (const int*)d_in[10];
    float* out = (float*)d_out;

    int*   map  = (int*)d_ws;
    float* comb = (float*)((char*)d_ws + (size_t)BATCH * CELLS * 4);

    (void)hipMemsetAsync(map, 0xFF, (size_t)BATCH * CELLS * 4, stream);  // all -1
    // DIAGNOSTIC: pfe is idempotent; run 5x so dur_us = base + 4*t_pfe.
    for (int i = 0; i < 5; ++i) {
        pfe_kernel<<<PTOT / 4, 256, 0, stream>>>(pillars, w1, bn1, w2, bn2,
                                                 wf1, wf2, fbn1, fbn2,
                                                 coords, nump, comb, map);
    }
    emit_kernel<<<(BATCH * CELLS) / TCELLS, 256, 0, stream>>>(map, comb, out);
}

// Round 7
// 89.161 us; speedup vs baseline: 3.1333x; 3.1333x over previous
//
#include <hip/hip_runtime.h>
#include <math.h>

#define NXC 432
#define NYC 496
#define CELLS (NYC * NXC)          // 214272
#define BATCH 4
#define PTOT 48000
#define EPSC 1e-3f
#define TCELLS 128                 // emit tile (CELLS % 128 == 0)

typedef float f4v    __attribute__((ext_vector_type(4)));
typedef float f32x16 __attribute__((ext_vector_type(16)));
typedef __bf16 bf16x8 __attribute__((ext_vector_type(8)));

// ---------------------------------------------------------------------------
// Kernel 1: per-pillar fused dual-PFN via MFMA.
// One wave per pillar. H(32pts x 128ch) = X(32x8) . W'(8x128), done as 4x
// mfma_f32_32x32x16_bf16 (channels tiled by 32). Pillar-dependent constants
// (mean/center via C0) are added AFTER the max over points (max commutes).
// bf16 hi/lo split of X occupies the spare K=8..15 slots -> X is exact,
// only W' carries bf16 rounding.
// Verified layouts (learn_hip m74/m101): D col=lane&31,
// row=(reg&3)+8*(reg>>2)+4*(lane>>5); A row=lane&31, k=(lane>>5)*8+e;
// B col=lane&31, k=(lane>>5)*8+e.
// ---------------------------------------------------------------------------
__global__ __launch_bounds__(256) void pfe_kernel(
    const float* __restrict__ pillars, const float* __restrict__ w1,
    const float* __restrict__ bn1, const float* __restrict__ w2,
    const float* __restrict__ bn2, const float* __restrict__ wf1,
    const float* __restrict__ wf2, const float* __restrict__ fbn1,
    const float* __restrict__ fbn2, const int* __restrict__ coords,
    const int* __restrict__ num_points, float* __restrict__ comb,
    int* __restrict__ map)
{
    const int tid  = threadIdx.x;
    const int lane = tid & 63;
    const int ln   = lane & 31;               // point index / channel-in-tile
    const bool hi  = lane >= 32;
    const int p = __builtin_amdgcn_readfirstlane(blockIdx.x * 4 + (tid >> 6));
    const float* __restrict__ pl = pillars + (size_t)p * 256;

    // all lanes load point ln's 8 features (hi half duplicates; coalesced 1KB)
    const f4v v0 = *(const f4v*)(pl + ln * 8);
    const f4v v1 = *(const f4v*)(pl + ln * 8 + 4);

    // mean xyz over all 32 points (reference does NOT mask); each 32-half
    // reduces independently to identical sums.
    float sx = v0.x, sy = v0.y, sz = v0.z;
#pragma unroll
    for (int off = 1; off <= 16; off <<= 1) {
        sx += __shfl_xor(sx, off);
        sy += __shfl_xor(sy, off);
        sz += __shfl_xor(sz, off);
    }
    const float inv_np = 1.0f / (float)num_points[p];
    const float mxm = sx * inv_np, mym = sy * inv_np, mzm = sz * inv_np;

    const int c1 = coords[p * 4 + 1], c2 = coords[p * 4 + 2], c3 = coords[p * 4 + 3];
    const float cx = c3 * 0.16f + 0.08f;
    const float cy = c2 * 0.16f + (-39.6f);
    const float cz = c1 * 4.0f  + (-1.0f);

    // ---- folded coefficients for this lane's two channels: cA=ln, cB=ln+32
    float AXc[2], AYc[2], AZc[2], AIc[2], C0c[2];
    float Bc[2][8], C2c[2], WF1c[2], WF2c[2];
#pragma unroll
    for (int i = 0; i < 2; ++i) {
        const int c = ln + i * 32;
        const float s1 = bn1[c] * rsqrtf(bn1[192 + c] + EPSC);
        const float be1 = bn1[64 + c], bm1 = bn1[128 + c];
        const float w10 = w1[c],       w11 = w1[64 + c],  w12 = w1[128 + c];
        const float w13 = w1[192 + c], w14 = w1[256 + c], w15 = w1[320 + c];
        const float w16 = w1[384 + c], w17 = w1[448 + c], w18 = w1[512 + c];
        const float w19 = w1[576 + c];
        AXc[i] = (w10 + w14 + w17) * s1;
        AYc[i] = (w11 + w15 + w18) * s1;
        AZc[i] = (w12 + w16 + w19) * s1;
        AIc[i] = w13 * s1;
        C0c[i] = be1 - bm1 * s1
               - (mxm * w14 + mym * w15 + mzm * w16) * s1
               - (cx * w17 + cy * w18 + cz * w19) * s1;

        const float s2 = bn2[c] * rsqrtf(bn2[192 + c] + EPSC);
#pragma unroll
        for (int k = 0; k < 8; ++k) Bc[i][k] = w2[k * 64 + c] * s2;
        C2c[i] = bn2[64 + c] - bn2[128 + c] * s2;
        WF1c[i] = wf1[c];
        WF2c[i] = wf2[c];
    }

    // ---- A fragment: lo lanes carry bf16-hi of feats (k=0..7),
    //      hi lanes carry bf16-lo residual (k=8..15). X becomes exact.
    const float fe0 = v0.x, fe1 = v0.y, fe2 = v0.z, fe3 = v0.w;
    const float fe4 = v1.x, fe5 = v1.y, fe6 = v1.z, fe7 = v1.w;
    bf16x8 a;
    {
        const float f[8] = {fe0, fe1, fe2, fe3, fe4, fe5, fe6, fe7};
#pragma unroll
        for (int e = 0; e < 8; ++e) {
            const __bf16 h = (__bf16)f[e];
            const __bf16 l = (__bf16)(f[e] - (float)h);
            a[e] = hi ? l : h;
        }
    }

    // ---- B fragments (one 32-channel tile each). Both lane halves hold the
    //      SAME W' column (k=0..7 and k=8..15 duplicated for the A-split).
    const bf16x8 b0 = {(__bf16)AXc[0], (__bf16)AYc[0], (__bf16)AZc[0], (__bf16)AIc[0],
                       (__bf16)0.f, (__bf16)0.f, (__bf16)0.f, (__bf16)0.f};
    const bf16x8 b1 = {(__bf16)AXc[1], (__bf16)AYc[1], (__bf16)AZc[1], (__bf16)AIc[1],
                       (__bf16)0.f, (__bf16)0.f, (__bf16)0.f, (__bf16)0.f};
    const bf16x8 b2 = {(__bf16)Bc[0][0], (__bf16)Bc[0][1], (__bf16)Bc[0][2], (__bf16)Bc[0][3],
                       (__bf16)Bc[0][4], (__bf16)Bc[0][5], (__bf16)Bc[0][6], (__bf16)Bc[0][7]};
    const bf16x8 b3 = {(__bf16)Bc[1][0], (__bf16)Bc[1][1], (__bf16)Bc[1][2], (__bf16)Bc[1][3],
                       (__bf16)Bc[1][4], (__bf16)Bc[1][5], (__bf16)Bc[1][6], (__bf16)Bc[1][7]};

    f32x16 d0 = {0.f}, d1 = {0.f}, d2 = {0.f}, d3 = {0.f};
    d0 = __builtin_amdgcn_mfma_f32_32x32x16_bf16(a, b0, d0, 0, 0, 0);
    d1 = __builtin_amdgcn_mfma_f32_32x32x16_bf16(a, b1, d1, 0, 0, 0);
    d2 = __builtin_amdgcn_mfma_f32_32x32x16_bf16(a, b2, d2, 0, 0, 0);
    d3 = __builtin_amdgcn_mfma_f32_32x32x16_bf16(a, b3, d3, 0, 0, 0);

    // ---- max over points (rows): 15 in-lane max over regs + cross-half.
    float m0 = d0[0], m1 = d1[0], m2 = d2[0], m3 = d3[0];
#pragma unroll
    for (int r = 1; r < 16; ++r) {
        m0 = fmaxf(m0, d0[r]); m1 = fmaxf(m1, d1[r]);
        m2 = fmaxf(m2, d2[r]); m3 = fmaxf(m3, d3[r]);
    }
    m0 = fmaxf(m0, __shfl_xor(m0, 32));
    m1 = fmaxf(m1, __shfl_xor(m1, 32));
    m2 = fmaxf(m2, __shfl_xor(m2, 32));
    m3 = fmaxf(m3, __shfl_xor(m3, 32));

    // relu(bn(h)).max == max(0, max_n h' + C)  (BN affine folded; C post-max)
    const float f1A = fmaxf(m0 + C0c[0], 0.f);
    const float f1B = fmaxf(m1 + C0c[1], 0.f);
    const float f2A = fmaxf(m2 + C2c[0], 0.f);
    const float f2B = fmaxf(m3 + C2c[1], 0.f);

    // ---- attention scalars: each 32-half holds the full 64-channel set.
    float dd1 = f1A * WF1c[0] + f1B * WF1c[1];
    float dd2 = f2A * WF2c[0] + f2B * WF2c[1];
#pragma unroll
    for (int off = 1; off <= 16; off <<= 1) {
        dd1 += __shfl_xor(dd1, off);
        dd2 += __shfl_xor(dd2, off);
    }
    const float sc1 = (dd1 - fbn1[2]) * (fbn1[0] * rsqrtf(fbn1[3] + EPSC)) + fbn1[1];
    const float sc2 = (dd2 - fbn2[2]) * (fbn2[0] * rsqrtf(fbn2[3] + EPSC)) + fbn2[1];
    const float a0 = 1.0f / (1.0f + expf(sc2 - sc1));   // softmax weight of branch 1

    if (!hi) {
        comb[p * 64 + ln]      = fmaf(f1A - f2A, a0, f2A);
        comb[p * 64 + 32 + ln] = fmaf(f1B - f2B, a0, f2B);
    }
    if (lane == 0) {
        const int lin = c1 + c2 * NXC + c3;
        map[coords[p * 4 + 0] * CELLS + lin] = p;
    }
}

// ---------------------------------------------------------------------------
// Kernel 2: dense emit via LDS transpose. Empty cells (94%) skip the comb
// gather entirely and write zeros to LDS.
// ---------------------------------------------------------------------------
__global__ __launch_bounds__(256) void emit_kernel(
    const int* __restrict__ map, const float* __restrict__ comb,
    float* __restrict__ out)
{
    __shared__ float lds[64 * 132];           // [ch][cell], pad 132 words
    const int t = threadIdx.x;
    const int gbase = blockIdx.x * TCELLS;    // global cell base (tile in one batch)

    // phase 1: gather comb rows -> LDS transposed (skip loads for empty cells)
    {
        const int c = t >> 1;                 // cell within tile
        const int h = (t & 1) * 32;           // channel half
        const int m = map[gbase + c];
        float* dst = lds + h * 132 + c;
        if (m >= 0) {
            const float* src = comb + (size_t)m * 64 + h;
#pragma unroll
            for (int j = 0; j < 8; j++) {
                const float4 v = *(const float4*)(src + j * 4);
                dst[(j * 4 + 0) * 132] = v.x;
                dst[(j * 4 + 1) * 132] = v.y;
                dst[(j * 4 + 2) * 132] = v.z;
                dst[(j * 4 + 3) * 132] = v.w;
            }
        } else {
#pragma unroll
            for (int j = 0; j < 32; j++) dst[j * 132] = 0.f;
        }
    }
    __syncthreads();

    // phase 2: coalesced float4 nontemporal stores
    const int b = gbase / CELLS;
    const int L = gbase - b * CELLS;
    float* obase = out + (size_t)(b * 64) * CELLS + L;
#pragma unroll
    for (int r = 0; r < 8; r++) {
        const int idx = r * 256 + t;
        const int f = idx >> 5;               // channel
        const int g = idx & 31;               // float4 group along cells
        const f4v v = *(const f4v*)(lds + f * 132 + g * 4);
        __builtin_nontemporal_store(v, (f4v*)(obase + (size_t)f * CELLS + g * 4));
    }
}

extern "C" void kernel_launch(void* const* d_in, const int* in_sizes, int n_in,
                              void* d_out, int out_size, void* d_ws, size_t ws_size,
                              hipStream_t stream) {
    const float* pillars = (const float*)d_in[0];
    const float* w1      = (const float*)d_in[1];
    const float* bn1     = (const float*)d_in[2];
    const float* w2      = (const float*)d_in[3];
    const float* bn2     = (const float*)d_in[4];
    const float* wf1     = (const float*)d_in[5];
    const float* wf2     = (const float*)d_in[6];
    const float* fbn1    = (const float*)d_in[7];
    const float* fbn2    = (const float*)d_in[8];
    const int*   coords  = (const int*)d_in[9];
    const int*   nump    = (const int*)d_in[10];
    float* out = (float*)d_out;

    int*   map  = (int*)d_ws;
    float* comb = (float*)((char*)d_ws + (size_t)BATCH * CELLS * 4);

    (void)hipMemsetAsync(map, 0xFF, (size_t)BATCH * CELLS * 4, stream);  // all -1
    pfe_kernel<<<PTOT / 4, 256, 0, stream>>>(pillars, w1, bn1, w2, bn2,
                                             wf1, wf2, fbn1, fbn2,
                                             coords, nump, comb, map);
    emit_kernel<<<(BATCH * CELLS) / TCELLS, 256, 0, stream>>>(map, comb, out);
}